// Round 9
// baseline (245.433 us; speedup 1.0000x reference)
//
#include <hip/hip_runtime.h>
#include <hip/hip_bf16.h>

typedef __attribute__((ext_vector_type(4))) float f32x4;
typedef __attribute__((ext_vector_type(8))) short short8;
typedef unsigned short u16;

#define NROWS 8192
#define DM 1024
#define EPSF 1e-8f
#define NRB 64        // 128-row blocks
#define NSLOT 64      // contributor lists per row

// async global->LDS, 16B per lane, wave-uniform LDS base (rule #21: linear dest,
// inverse-swizzled SOURCE, swizzle applied again on the ds_read side)
#define GLDS(gsrc, ldst) __builtin_amdgcn_global_load_lds(                 \
    (const __attribute__((address_space(1))) void*)(gsrc),                 \
    (__attribute__((address_space(3))) void*)(ldst), 16, 0, 0)

static __device__ __forceinline__ u16 f2bf(float x) {
  unsigned u = __float_as_uint(x);
  u += 0x7fffu + ((u >> 16) & 1u);   // RNE
  return (u16)(u >> 16);
}

// insert v into descending-sorted S[9]; all indices compile-time (stays in VGPRs)
static __device__ __forceinline__ void topk9_insert(float (&S)[9], float v) {
  if (v <= S[8]) return;
  S[8] = v;
#pragma unroll
  for (int q = 8; q > 0; --q) {
    float a = S[q - 1], b = S[q];
    S[q - 1] = fmaxf(a, b);
    S[q]     = fminf(a, b);
  }
}

// issue one K-step's async staging (A+B tiles) into the given LDS buffers
static __device__ __forceinline__ void stage_tile(
    const char* __restrict__ Abase, const char* __restrict__ Bbase,
    int k0b, char* smem, int aoff, int boff, int t, int wchunk)
{
#pragma unroll
  for (int it = 0; it < 4; ++it) {
    const int p  = it * 256 + t;           // chunk id 0..1023 (rematerializable)
    const int so = (p >> 3) * (DM * 2) + (((p & 7) ^ ((p >> 3) & 7)) * 16);
    GLDS(Abase + k0b + so, smem + aoff + (it * 256 + wchunk) * 16);
    GLDS(Bbase + k0b + so, smem + boff + (it * 256 + wchunk) * 16);
  }
}

// one K-step of MFMA from staged LDS buffers
static __device__ __forceinline__ void compute_tile(
    f32x4 (&acc)[4][4], const u16* __restrict__ As, const u16* __restrict__ Bs,
    int lane, int wr, int wc)
{
#pragma unroll
  for (int ks = 0; ks < 2; ++ks) {
    const int co = ((ks * 4 + (lane >> 4)) ^ (lane & 7)) * 8;   // i/j-invariant
    short8 b[4];
#pragma unroll
    for (int j = 0; j < 4; ++j)
      b[j] = *(const short8*)(Bs + (wc + j * 16 + (lane & 15)) * 64 + co);
#pragma unroll
    for (int i = 0; i < 4; ++i) {
      const short8 a = *(const short8*)(As + (wr + i * 16 + (lane & 15)) * 64 + co);
#pragma unroll
      for (int j = 0; j < 4; ++j)
        acc[i][j] = __builtin_amdgcn_mfma_f32_16x16x32_bf16(a, b[j], acc[i][j], 0, 0, 0);
    }
  }
}

// ---------------- kernel 1: row norm -> bf16 F, content logits ----------------
__global__ __launch_bounds__(256) void k_rowprep(
    const float* __restrict__ H, const float* __restrict__ Wc,
    const float* __restrict__ bc, u16* __restrict__ F, float* __restrict__ CL)
{
  const int r = blockIdx.x;
  const int t = threadIdx.x;
  const int lane = t & 63;
  const int w = t >> 6;

  const float4 h  = ((const float4*)(H  + (size_t)r * DM))[t];
  const float4 c0 = ((const float4*)(Wc + 0 * DM))[t];
  const float4 c1 = ((const float4*)(Wc + 1 * DM))[t];
  const float4 c2 = ((const float4*)(Wc + 2 * DM))[t];

  float ss = h.x*h.x + h.y*h.y + h.z*h.z + h.w*h.w;
  float d0 = h.x*c0.x + h.y*c0.y + h.z*c0.z + h.w*c0.w;
  float d1 = h.x*c1.x + h.y*c1.y + h.z*c1.z + h.w*c1.w;
  float d2 = h.x*c2.x + h.y*c2.y + h.z*c2.z + h.w*c2.w;

#pragma unroll
  for (int off = 32; off > 0; off >>= 1) {
    ss += __shfl_down(ss, off);
    d0 += __shfl_down(d0, off);
    d1 += __shfl_down(d1, off);
    d2 += __shfl_down(d2, off);
  }
  __shared__ float red[4][4];
  __shared__ float bcast;
  if (lane == 0) { red[w][0] = ss; red[w][1] = d0; red[w][2] = d1; red[w][3] = d2; }
  __syncthreads();
  if (t == 0) {
    float S  = red[0][0] + red[1][0] + red[2][0] + red[3][0];
    float D0 = red[0][1] + red[1][1] + red[2][1] + red[3][1];
    float D1 = red[0][2] + red[1][2] + red[2][2] + red[3][2];
    float D2 = red[0][3] + red[1][3] + red[2][3] + red[3][3];
    bcast = 1.0f / (sqrtf(S) + EPSF);
    CL[r*3+0] = D0 + bc[0];
    CL[r*3+1] = D1 + bc[1];
    CL[r*3+2] = D2 + bc[2];
  }
  __syncthreads();
  const float invn = bcast;
  ushort4 o;
  o.x = f2bf(h.x * invn); o.y = f2bf(h.y * invn);
  o.z = f2bf(h.z * invn); o.w = f2bf(h.w * invn);
  ((ushort4*)(F + (size_t)r * DM))[t] = o;
}

// ---------------- kernel 2: symmetric sim GEMM + fused top-9 ----------------
// Upper-triangle tiles only: grid 64x64, blocks with cb<rb exit. Each block
// computes ONE 128x128 tile over full K=1024 (2-phase dbuf), spills all 4
// quadrants to a [128][128] rotate-slot LDS tile, then row-scans (feeds rows
// R0..) AND col-scans (feeds rows C0.., skipped on diagonal). Values identical
// to the full-matrix version; GEMM/stage/spill work halves.
__global__ __launch_bounds__(256, 2) void k_simtopk(
    const u16* __restrict__ F, float* __restrict__ partials)
{
  const int rb = blockIdx.y;
  const int cb = blockIdx.x;
  if (cb < rb) return;                     // lower triangle: nothing to do

  __shared__ char smem[65536];
  u16*   A0s = (u16*)smem;                 // [128][64] bf16 swizzled, 16 KiB
  u16*   B0s = (u16*)(smem + 16384);
  u16*   A1s = (u16*)(smem + 32768);
  u16*   B1s = (u16*)(smem + 49152);
  float* Cs  = (float*)smem;               // [128][128] f32 spill overlay (64 KiB)
  float* Ms  = (float*)smem;               // [128][18] merge overlay (9 KiB)

  const int t    = threadIdx.x;
  const int lane = t & 63;
  const int w    = t >> 6;
  const int wr   = (w >> 1) * 64;
  const int wc   = (w & 1) * 64;
  const int R0   = rb * 128;
  const int C0   = cb * 128;
  const int wchunk = t & 192;              // wave-uniform chunk base within 256

  f32x4 acc[4][4];
#pragma unroll
  for (int i = 0; i < 4; ++i)
#pragma unroll
    for (int j = 0; j < 4; ++j)
      acc[i][j] = {0.f, 0.f, 0.f, 0.f};

  const char* Abase = (const char*)(F + (size_t)R0 * DM);
  const char* Bbase = (const char*)(F + (size_t)C0 * DM);

  // 2-phase double-buffered K-loop (16 chunks of BK=64)
  stage_tile(Abase, Bbase, 0, smem, 0, 16384, t, wchunk);
  __syncthreads();                         // drains vmcnt(0): buf0 ready
  for (int kkp = 0; kkp < 8; ++kkp) {
    const int kb = kkp * 256;
    stage_tile(Abase, Bbase, kb + 128, smem, 32768, 49152, t, wchunk);
    compute_tile(acc, A0s, B0s, lane, wr, wc);
    __syncthreads();                       // buf1 ready; buf0 reads done
    if (kkp < 7)
      stage_tile(Abase, Bbase, kb + 256, smem, 0, 16384, t, wchunk);
    compute_tile(acc, A1s, B1s, lane, wr, wc);
    __syncthreads();                       // buf0 ready; buf1 reads done
  }

  // spill ALL quadrants: waves own disjoint 64x64 quadrants; phys slot =
  // ((col>>2)+row)&31 -> writes and both scans are <=2-way (free)
#pragma unroll
  for (int i = 0; i < 4; ++i)
#pragma unroll
    for (int j = 0; j < 4; ++j)
#pragma unroll
      for (int q = 0; q < 4; ++q) {
        const int rr = wr + i * 16 + (lane >> 4) * 4 + q;
        const int cc = wc + j * 16 + (lane & 15);
        const int slot = ((cc >> 2) + rr) & 31;
        Cs[rr * 128 + (slot << 2) + (cc & 3)] = acc[i][j][q];
      }
  __syncthreads();

  // row-scan: 2 threads/row, 64-col strips, vectorized b128
  float sR[9];
#pragma unroll
  for (int q = 0; q < 9; ++q) sR[q] = -1e30f;
  {
    const int row   = t >> 1;
    const int cbase = (t & 1) * 64;
    const float* crow = Cs + row * 128;
#pragma unroll
    for (int g = 0; g < 16; ++g) {
      const int c0   = cbase + 4 * g;
      const int slot = ((c0 >> 2) + row) & 31;
      const f32x4 v  = *(const f32x4*)(crow + (slot << 2));
      const float m  = fmaxf(fmaxf(v.x, v.y), fmaxf(v.z, v.w));
      if (m > sR[8]) {
        topk9_insert(sR, v.x); topk9_insert(sR, v.y);
        topk9_insert(sR, v.z); topk9_insert(sR, v.w);
      }
    }
  }

  // col-scan (off-diagonal only): 2 threads/col, 64-row strips, scalar reads
  float sC[9];
#pragma unroll
  for (int q = 0; q < 9; ++q) sC[q] = -1e30f;
  if (rb != cb) {
    const int col   = t >> 1;
    const int rbase = (t & 1) * 64;
    for (int r = 0; r < 64; ++r) {
      const int rr   = rbase + r;
      const int slot = ((col >> 2) + rr) & 31;
      const float v  = Cs[rr * 128 + (slot << 2) + (col & 3)];
      topk9_insert(sC, v);
    }
  }
  __syncthreads();                         // all Cs reads done before overlay reuse

  // merge row lists (2 per row) -> partials[R0+row][slot=cb]
#pragma unroll
  for (int q = 0; q < 9; ++q) Ms[(t >> 1) * 18 + (t & 1) * 9 + q] = sR[q];
  __syncthreads();
  if (t < 128) {
    const float* row = Ms + t * 18;
    float T[9];
#pragma unroll
    for (int q = 0; q < 9; ++q) T[q] = row[q];
    for (int gq = 0; gq < 9; ++gq) {
      const float v = row[9 + gq];
      if (v <= T[8]) break;
      topk9_insert(T, v);
    }
    float* dst = partials + ((size_t)(R0 + t) * NSLOT + cb) * 9;
#pragma unroll
    for (int q = 0; q < 9; ++q) dst[q] = T[q];
  }
  __syncthreads();

  // merge col lists (2 per col) -> partials[C0+col][slot=rb]  (off-diagonal only)
  if (rb != cb) {
#pragma unroll
    for (int q = 0; q < 9; ++q) Ms[(t >> 1) * 18 + (t & 1) * 9 + q] = sC[q];
    __syncthreads();
    if (t < 128) {
      const float* row = Ms + t * 18;
      float T[9];
#pragma unroll
      for (int q = 0; q < 9; ++q) T[q] = row[q];
      for (int gq = 0; gq < 9; ++gq) {
        const float v = row[9 + gq];
        if (v <= T[8]) break;
        topk9_insert(T, v);
      }
      float* dst = partials + ((size_t)(C0 + t) * NSLOT + rb) * 9;
#pragma unroll
      for (int q = 0; q < 9; ++q) dst[q] = T[q];
    }
  }
}

// ---------------- kernel 3: merge partials, features, MLP, mix, softmax ----------------
__global__ __launch_bounds__(256) void k_finalize(
    const float* __restrict__ partials, const float* __restrict__ CL,
    const float* __restrict__ W1, const float* __restrict__ b1,
    const float* __restrict__ W2, const float* __restrict__ b2,
    const float* __restrict__ alpha, float* __restrict__ out)
{
  const int n = blockIdx.x * 256 + threadIdx.x;
  if (n >= NROWS) return;
  const float* p = partials + (size_t)n * (NSLOT * 9);
  float S[9];
#pragma unroll
  for (int q = 0; q < 9; ++q) S[q] = -1e30f;
  for (int grp = 0; grp < NSLOT; ++grp) {
    for (int gq = 0; gq < 9; ++gq) {
      const float v = p[grp * 9 + gq];
      if (v <= S[8]) break;               // groups are descending
      topk9_insert(S, v);
    }
  }
  // S[0] is the self-similarity (max, appears exactly once) -> dropped
  float sum = 0.f, sumsq = 0.f;
#pragma unroll
  for (int q = 1; q < 9; ++q) { sum += S[q]; sumsq += S[q] * S[q]; }
  const float mean_s  = sum * 0.125f;
  float var = (sumsq - 8.f * mean_s * mean_s) * (1.f / 7.f);  // ddof=1
  var = fmaxf(var, 0.f);
  const float tree    = sqrtf(var);
  const float density = 1.f - mean_s;
  const float outlier = (1.f - S[8]) / (density + EPSF);      // min sim = max dist

  float a0 = b2[0], a1 = b2[1], a2 = b2[2];
#pragma unroll
  for (int j = 0; j < 32; ++j) {
    float hj = W1[j*3+0]*tree + W1[j*3+1]*density + W1[j*3+2]*outlier + b1[j];
    hj = fmaxf(hj, 0.f);
    a0 += W2[j]      * hj;
    a1 += W2[32 + j] * hj;
    a2 += W2[64 + j] * hj;
  }
  const float mix = 1.f / (1.f + expf(-alpha[0]));
  const float im  = 1.f - mix;
  const float l0 = mix * CL[n*3+0] + im * a0;
  const float l1 = mix * CL[n*3+1] + im * a1;
  const float l2 = mix * CL[n*3+2] + im * a2;
  const float mx = fmaxf(l0, fmaxf(l1, l2));
  const float e0 = expf(l0 - mx), e1 = expf(l1 - mx), e2 = expf(l2 - mx);
  const float inv = 1.f / (e0 + e1 + e2);
  out[n*3+0] = e0 * inv;
  out[n*3+1] = e1 * inv;
  out[n*3+2] = e2 * inv;
  float* outl = out + NROWS * 3;
  outl[n*3+0] = l0;
  outl[n*3+1] = l1;
  outl[n*3+2] = l2;
}

extern "C" void kernel_launch(void* const* d_in, const int* in_sizes, int n_in,
                              void* d_out, int out_size, void* d_ws, size_t ws_size,
                              hipStream_t stream) {
  const float* H     = (const float*)d_in[0];
  const float* Wc    = (const float*)d_in[1];
  const float* bc    = (const float*)d_in[2];
  const float* W1    = (const float*)d_in[3];
  const float* b1    = (const float*)d_in[4];
  const float* W2    = (const float*)d_in[5];
  const float* b2    = (const float*)d_in[6];
  const float* alpha = (const float*)d_in[7];
  float* out = (float*)d_out;

  char* ws = (char*)d_ws;
  u16*   F        = (u16*)ws;                               // 16 MiB
  float* CL       = (float*)(ws + 16777216);                // 96 KiB
  float* partials = (float*)(ws + 16777216 + 98304);        // 8192*64*9*4 = 18 MiB

  k_rowprep<<<NROWS, 256, 0, stream>>>(H, Wc, bc, F, CL);
  dim3 g2(NRB, NRB);                       // upper triangle does the work
  k_simtopk<<<g2, 256, 0, stream>>>(F, partials);
  k_finalize<<<NROWS / 256, 256, 0, stream>>>(partials, CL, W1, b1, W2, b2, alpha, out);
}

// Round 10
// 211.687 us; speedup vs baseline: 1.1594x; 1.1594x over previous
//
#include <hip/hip_runtime.h>
#include <hip/hip_bf16.h>

typedef __attribute__((ext_vector_type(4))) float f32x4;
typedef __attribute__((ext_vector_type(8))) short short8;
typedef unsigned short u16;

#define NROWS 8192
#define DM 1024
#define EPSF 1e-8f
#define NRB 64        // 128-row blocks
#define NSLOT 64      // contributor lists per row
#define NTILES 2080   // NRB*(NRB+1)/2 upper-triangle tiles

// async global->LDS, 16B per lane, wave-uniform LDS base (rule #21: linear dest,
// inverse-swizzled SOURCE, swizzle applied again on the ds_read side)
#define GLDS(gsrc, ldst) __builtin_amdgcn_global_load_lds(                 \
    (const __attribute__((address_space(1))) void*)(gsrc),                 \
    (__attribute__((address_space(3))) void*)(ldst), 16, 0, 0)

static __device__ __forceinline__ u16 f2bf(float x) {
  unsigned u = __float_as_uint(x);
  u += 0x7fffu + ((u >> 16) & 1u);   // RNE
  return (u16)(u >> 16);
}

// insert v into descending-sorted S[9]; all indices compile-time (stays in VGPRs)
static __device__ __forceinline__ void topk9_insert(float (&S)[9], float v) {
  if (v <= S[8]) return;
  S[8] = v;
#pragma unroll
  for (int q = 8; q > 0; --q) {
    float a = S[q - 1], b = S[q];
    S[q - 1] = fmaxf(a, b);
    S[q]     = fminf(a, b);
  }
}

// vectorized scan of a 64-col strip of one spilled row (rotate-slot layout)
static __device__ __forceinline__ void scan_row_strip(
    float (&S)[9], const float* __restrict__ crow, int row, int cbase) {
#pragma unroll
  for (int g = 0; g < 16; ++g) {
    const int c0   = cbase + 4 * g;
    const int slot = ((c0 >> 2) + row) & 31;           // additive rotate, 2-way free
    const f32x4 v  = *(const f32x4*)(crow + (slot << 2));
    const float m  = fmaxf(fmaxf(v.x, v.y), fmaxf(v.z, v.w));
    if (m > S[8]) {
      topk9_insert(S, v.x); topk9_insert(S, v.y);
      topk9_insert(S, v.z); topk9_insert(S, v.w);
    }
  }
}

// issue one K-step's async staging (A+B tiles) into the given LDS buffers
static __device__ __forceinline__ void stage_tile(
    const char* __restrict__ Abase, const char* __restrict__ Bbase,
    int k0b, char* smem, int aoff, int boff, int t, int wchunk)
{
#pragma unroll
  for (int it = 0; it < 4; ++it) {
    const int p  = it * 256 + t;           // chunk id 0..1023 (rematerializable)
    const int so = (p >> 3) * (DM * 2) + (((p & 7) ^ ((p >> 3) & 7)) * 16);
    GLDS(Abase + k0b + so, smem + aoff + (it * 256 + wchunk) * 16);
    GLDS(Bbase + k0b + so, smem + boff + (it * 256 + wchunk) * 16);
  }
}

// one K-step of MFMA from staged LDS buffers
static __device__ __forceinline__ void compute_tile(
    f32x4 (&acc)[4][4], const u16* __restrict__ As, const u16* __restrict__ Bs,
    int lane, int wr, int wc)
{
#pragma unroll
  for (int ks = 0; ks < 2; ++ks) {
    const int co = ((ks * 4 + (lane >> 4)) ^ (lane & 7)) * 8;   // i/j-invariant
    short8 b[4];
#pragma unroll
    for (int j = 0; j < 4; ++j)
      b[j] = *(const short8*)(Bs + (wc + j * 16 + (lane & 15)) * 64 + co);
#pragma unroll
    for (int i = 0; i < 4; ++i) {
      const short8 a = *(const short8*)(As + (wr + i * 16 + (lane & 15)) * 64 + co);
#pragma unroll
      for (int j = 0; j < 4; ++j)
        acc[i][j] = __builtin_amdgcn_mfma_f32_16x16x32_bf16(a, b[j], acc[i][j], 0, 0, 0);
    }
  }
}

// ---------------- kernel 1: row norm -> bf16 F, content logits ----------------
__global__ __launch_bounds__(256) void k_rowprep(
    const float* __restrict__ H, const float* __restrict__ Wc,
    const float* __restrict__ bc, u16* __restrict__ F, float* __restrict__ CL)
{
  const int r = blockIdx.x;
  const int t = threadIdx.x;
  const int lane = t & 63;
  const int w = t >> 6;

  const float4 h  = ((const float4*)(H  + (size_t)r * DM))[t];
  const float4 c0 = ((const float4*)(Wc + 0 * DM))[t];
  const float4 c1 = ((const float4*)(Wc + 1 * DM))[t];
  const float4 c2 = ((const float4*)(Wc + 2 * DM))[t];

  float ss = h.x*h.x + h.y*h.y + h.z*h.z + h.w*h.w;
  float d0 = h.x*c0.x + h.y*c0.y + h.z*c0.z + h.w*c0.w;
  float d1 = h.x*c1.x + h.y*c1.y + h.z*c1.z + h.w*c1.w;
  float d2 = h.x*c2.x + h.y*c2.y + h.z*c2.z + h.w*c2.w;

#pragma unroll
  for (int off = 32; off > 0; off >>= 1) {
    ss += __shfl_down(ss, off);
    d0 += __shfl_down(d0, off);
    d1 += __shfl_down(d1, off);
    d2 += __shfl_down(d2, off);
  }
  __shared__ float red[4][4];
  __shared__ float bcast;
  if (lane == 0) { red[w][0] = ss; red[w][1] = d0; red[w][2] = d1; red[w][3] = d2; }
  __syncthreads();
  if (t == 0) {
    float S  = red[0][0] + red[1][0] + red[2][0] + red[3][0];
    float D0 = red[0][1] + red[1][1] + red[2][1] + red[3][1];
    float D1 = red[0][2] + red[1][2] + red[2][2] + red[3][2];
    float D2 = red[0][3] + red[1][3] + red[2][3] + red[3][3];
    bcast = 1.0f / (sqrtf(S) + EPSF);
    CL[r*3+0] = D0 + bc[0];
    CL[r*3+1] = D1 + bc[1];
    CL[r*3+2] = D2 + bc[2];
  }
  __syncthreads();
  const float invn = bcast;
  ushort4 o;
  o.x = f2bf(h.x * invn); o.y = f2bf(h.y * invn);
  o.z = f2bf(h.z * invn); o.w = f2bf(h.w * invn);
  ((ushort4*)(F + (size_t)r * DM))[t] = o;
}

// ---------------- kernel 2: symmetric sim GEMM + fused top-9 ----------------
// Compact 1-D grid over the 2080 upper-triangle tiles. Per block: 128x128 tile
// over full K (2-phase dbuf), spill normal -> vectorized row-scan (feeds rows
// R0..), then spill TRANSPOSED (b128 stores, lane's f32x4 is contiguous there)
// -> vectorized scan again (feeds rows C0.., off-diagonal only).
__global__ __launch_bounds__(256, 2) void k_simtopk(
    const u16* __restrict__ F, float* __restrict__ partials)
{
  // decode linear tile id -> (rb, cb), cb >= rb
  const int idx = blockIdx.x;
  int rb = (int)(64.5 - sqrt(4160.25 - 2.0 * (double)idx));
  while (rb * NRB - rb * (rb - 1) / 2 > idx) --rb;
  while ((rb + 1) * NRB - (rb + 1) * rb / 2 <= idx) ++rb;
  const int cb = rb + (idx - (rb * NRB - rb * (rb - 1) / 2));

  __shared__ char smem[65536];
  u16*   A0s = (u16*)smem;                 // [128][64] bf16 swizzled, 16 KiB
  u16*   B0s = (u16*)(smem + 16384);
  u16*   A1s = (u16*)(smem + 32768);
  u16*   B1s = (u16*)(smem + 49152);
  float* Cs  = (float*)smem;               // [128][128] f32 spill overlay (64 KiB)
  float* Ms  = (float*)smem;               // [128][18] merge overlay (9 KiB)

  const int t    = threadIdx.x;
  const int lane = t & 63;
  const int w    = t >> 6;
  const int wr   = (w >> 1) * 64;
  const int wc   = (w & 1) * 64;
  const int R0   = rb * 128;
  const int C0   = cb * 128;
  const int wchunk = t & 192;              // wave-uniform chunk base within 256

  f32x4 acc[4][4];
#pragma unroll
  for (int i = 0; i < 4; ++i)
#pragma unroll
    for (int j = 0; j < 4; ++j)
      acc[i][j] = {0.f, 0.f, 0.f, 0.f};

  const char* Abase = (const char*)(F + (size_t)R0 * DM);
  const char* Bbase = (const char*)(F + (size_t)C0 * DM);

  // 2-phase double-buffered K-loop (16 chunks of BK=64)
  stage_tile(Abase, Bbase, 0, smem, 0, 16384, t, wchunk);
  __syncthreads();                         // drains vmcnt(0): buf0 ready
  for (int kkp = 0; kkp < 8; ++kkp) {
    const int kb = kkp * 256;
    stage_tile(Abase, Bbase, kb + 128, smem, 32768, 49152, t, wchunk);
    compute_tile(acc, A0s, B0s, lane, wr, wc);
    __syncthreads();                       // buf1 ready; buf0 reads done
    if (kkp < 7)
      stage_tile(Abase, Bbase, kb + 256, smem, 0, 16384, t, wchunk);
    compute_tile(acc, A1s, B1s, lane, wr, wc);
    __syncthreads();                       // buf0 ready; buf1 reads done
  }

  // ---- pass 1: normal spill (scalar), vectorized row-scan ----
  // phys slot = ((col>>2)+row)&31 : writes <=2-way, reads exactly 2-way (free)
#pragma unroll
  for (int i = 0; i < 4; ++i)
#pragma unroll
    for (int j = 0; j < 4; ++j)
#pragma unroll
      for (int q = 0; q < 4; ++q) {
        const int rr = wr + i * 16 + (lane >> 4) * 4 + q;
        const int cc = wc + j * 16 + (lane & 15);
        const int slot = ((cc >> 2) + rr) & 31;
        Cs[rr * 128 + (slot << 2) + (cc & 3)] = acc[i][j][q];
      }
  __syncthreads();

  float sR[9];
#pragma unroll
  for (int q = 0; q < 9; ++q) sR[q] = -1e30f;
  scan_row_strip(sR, Cs + (t >> 1) * 128, t >> 1, (t & 1) * 64);
  __syncthreads();                         // Cs reads done before Ms overlay write

  // merge row lists (2 per row) -> partials[slot=cb][R0+row]
#pragma unroll
  for (int q = 0; q < 9; ++q) Ms[(t >> 1) * 18 + (t & 1) * 9 + q] = sR[q];
  __syncthreads();
  if (t < 128) {
    const float* row = Ms + t * 18;
    float T[9];
#pragma unroll
    for (int q = 0; q < 9; ++q) T[q] = row[q];
    for (int gq = 0; gq < 9; ++gq) {
      const float v = row[9 + gq];
      if (v <= T[8]) break;
      topk9_insert(T, v);
    }
    float* dst = partials + ((size_t)cb * NROWS + R0 + t) * 9;
#pragma unroll
    for (int q = 0; q < 9; ++q) dst[q] = T[q];
  }

  // ---- pass 2 (off-diagonal only): transposed spill (b128), scan again ----
  if (rb != cb) {
    __syncthreads();                       // Ms merge reads done; reuse all 64 KiB
    // T[cc][rr] = tile(rr,cc): lane's acc[i][j] f32x4 (4 consecutive rr, one cc)
    // is CONTIGUOUS in transposed layout -> single b128 store per fragment.
#pragma unroll
    for (int i = 0; i < 4; ++i) {
      const int rr0 = wr + i * 16 + (lane >> 4) * 4;
#pragma unroll
      for (int j = 0; j < 4; ++j) {
        const int cc   = wc + j * 16 + (lane & 15);
        const int slot = ((rr0 >> 2) + cc) & 31;
        *(f32x4*)(Cs + cc * 128 + (slot << 2)) = acc[i][j];
      }
    }
    __syncthreads();

    float sC[9];
#pragma unroll
    for (int q = 0; q < 9; ++q) sC[q] = -1e30f;
    scan_row_strip(sC, Cs + (t >> 1) * 128, t >> 1, (t & 1) * 64);
    __syncthreads();                       // Cs reads done before Ms overlay write

#pragma unroll
    for (int q = 0; q < 9; ++q) Ms[(t >> 1) * 18 + (t & 1) * 9 + q] = sC[q];
    __syncthreads();
    if (t < 128) {
      const float* row = Ms + t * 18;
      float T[9];
#pragma unroll
      for (int q = 0; q < 9; ++q) T[q] = row[q];
      for (int gq = 0; gq < 9; ++gq) {
        const float v = row[9 + gq];
        if (v <= T[8]) break;
        topk9_insert(T, v);
      }
      float* dst = partials + ((size_t)rb * NROWS + C0 + t) * 9;
#pragma unroll
      for (int q = 0; q < 9; ++q) dst[q] = T[q];
    }
  }
}

// ---------------- kernel 3: merge partials, features, MLP, mix, softmax ----------------
// partials layout [slot][row][9]: adjacent threads read 36 B apart (coalesced-ish)
__global__ __launch_bounds__(256) void k_finalize(
    const float* __restrict__ partials, const float* __restrict__ CL,
    const float* __restrict__ W1, const float* __restrict__ b1,
    const float* __restrict__ W2, const float* __restrict__ b2,
    const float* __restrict__ alpha, float* __restrict__ out)
{
  const int n = blockIdx.x * 256 + threadIdx.x;
  if (n >= NROWS) return;
  float S[9];
#pragma unroll
  for (int q = 0; q < 9; ++q) S[q] = -1e30f;
  for (int grp = 0; grp < NSLOT; ++grp) {
    const float* p = partials + ((size_t)grp * NROWS + n) * 9;
    for (int gq = 0; gq < 9; ++gq) {
      const float v = p[gq];
      if (v <= S[8]) break;               // groups are descending
      topk9_insert(S, v);
    }
  }
  // S[0] is the self-similarity (max, appears exactly once) -> dropped
  float sum = 0.f, sumsq = 0.f;
#pragma unroll
  for (int q = 1; q < 9; ++q) { sum += S[q]; sumsq += S[q] * S[q]; }
  const float mean_s  = sum * 0.125f;
  float var = (sumsq - 8.f * mean_s * mean_s) * (1.f / 7.f);  // ddof=1
  var = fmaxf(var, 0.f);
  const float tree    = sqrtf(var);
  const float density = 1.f - mean_s;
  const float outlier = (1.f - S[8]) / (density + EPSF);      // min sim = max dist

  float a0 = b2[0], a1 = b2[1], a2 = b2[2];
#pragma unroll
  for (int j = 0; j < 32; ++j) {
    float hj = W1[j*3+0]*tree + W1[j*3+1]*density + W1[j*3+2]*outlier + b1[j];
    hj = fmaxf(hj, 0.f);
    a0 += W2[j]      * hj;
    a1 += W2[32 + j] * hj;
    a2 += W2[64 + j] * hj;
  }
  const float mix = 1.f / (1.f + expf(-alpha[0]));
  const float im  = 1.f - mix;
  const float l0 = mix * CL[n*3+0] + im * a0;
  const float l1 = mix * CL[n*3+1] + im * a1;
  const float l2 = mix * CL[n*3+2] + im * a2;
  const float mx = fmaxf(l0, fmaxf(l1, l2));
  const float e0 = expf(l0 - mx), e1 = expf(l1 - mx), e2 = expf(l2 - mx);
  const float inv = 1.f / (e0 + e1 + e2);
  out[n*3+0] = e0 * inv;
  out[n*3+1] = e1 * inv;
  out[n*3+2] = e2 * inv;
  float* outl = out + NROWS * 3;
  outl[n*3+0] = l0;
  outl[n*3+1] = l1;
  outl[n*3+2] = l2;
}

extern "C" void kernel_launch(void* const* d_in, const int* in_sizes, int n_in,
                              void* d_out, int out_size, void* d_ws, size_t ws_size,
                              hipStream_t stream) {
  const float* H     = (const float*)d_in[0];
  const float* Wc    = (const float*)d_in[1];
  const float* bc    = (const float*)d_in[2];
  const float* W1    = (const float*)d_in[3];
  const float* b1    = (const float*)d_in[4];
  const float* W2    = (const float*)d_in[5];
  const float* b2    = (const float*)d_in[6];
  const float* alpha = (const float*)d_in[7];
  float* out = (float*)d_out;

  char* ws = (char*)d_ws;
  u16*   F        = (u16*)ws;                               // 16 MiB
  float* CL       = (float*)(ws + 16777216);                // 96 KiB
  float* partials = (float*)(ws + 16777216 + 98304);        // 64*8192*9*4 = 18 MiB

  k_rowprep<<<NROWS, 256, 0, stream>>>(H, Wc, bc, F, CL);
  k_simtopk<<<NTILES, 256, 0, stream>>>(F, partials);
  k_finalize<<<NROWS / 256, 256, 0, stream>>>(partials, CL, W1, b1, W2, b2, alpha, out);
}